// Round 13
// baseline (1421.357 us; speedup 1.0000x reference)
//
#include <hip/hip_runtime.h>
#include <stdint.h>

#define N_NODES 50000
#define N_EDGES 200000
#define H 32
#define T_STEPS 8
#define NGROUPS (N_EDGES / 64)   // 3125
#define SCAN_B 196               // 196*256 = 50176 >= N_NODES
#define MSG_GRID 1024            // 3125/1024 -> 3 or 4 groups per block

typedef __attribute__((ext_vector_type(4))) float v4f;
typedef __attribute__((ext_vector_type(8))) _Float16 h8;

#define LO_SCALE 4096.0f
#define LO_DESCALE 2.44140625e-4f  // 1/4096

__device__ __forceinline__ uint32_t packh2(_Float16 a, _Float16 b) {
  return (uint32_t)__builtin_bit_cast(unsigned short, a) |
         ((uint32_t)__builtin_bit_cast(unsigned short, b) << 16);
}

// Transpose W1 (64x16 -> 16x64) so hidb's per-lane reads are coalesced. (R12 win)
__global__ void w1pack_kernel(const float* __restrict__ W1, float* __restrict__ W1P) {
  int o = threadIdx.x + blockIdx.x * blockDim.x;   // 1024 threads
  int d = o >> 4, k = o & 15;
  W1P[k * 64 + d] = W1[o];
}

// hid[e][d] = relu(edge_data[e].W1[d] + b1[d]), fp16 hi + scaled-lo. (R12: 108->~25us)
__global__ void hidb_kernel(const float* __restrict__ ed, const float* __restrict__ W1P,
                            const float* __restrict__ b1,
                            uint32_t* __restrict__ hidh, uint32_t* __restrict__ hidl) {
  int idx = blockIdx.x * blockDim.x + threadIdx.x;   // E*32 threads
  int e = idx >> 5, d2 = idx & 31;
  int d0 = d2 * 2;
  const float4* er = (const float4*)(ed + (size_t)e * 16);
  float2 bb = *(const float2*)(b1 + d0);
  float a0 = bb.x, a1 = bb.y;
#pragma unroll
  for (int k = 0; k < 4; k++) {
    float4 h = er[k];
    float2 w0 = *(const float2*)(W1P + (4 * k + 0) * 64 + d0);
    float2 w1 = *(const float2*)(W1P + (4 * k + 1) * 64 + d0);
    float2 w2 = *(const float2*)(W1P + (4 * k + 2) * 64 + d0);
    float2 w3 = *(const float2*)(W1P + (4 * k + 3) * 64 + d0);
    a0 += h.x * w0.x + h.y * w1.x + h.z * w2.x + h.w * w3.x;
    a1 += h.x * w0.y + h.y * w1.y + h.z * w2.y + h.w * w3.y;
  }
  a0 = fmaxf(a0, 0.f);
  a1 = fmaxf(a1, 0.f);
  _Float16 h0 = (_Float16)a0, h1 = (_Float16)a1;
  _Float16 l0 = (_Float16)((a0 - (float)h0) * LO_SCALE);
  _Float16 l1 = (_Float16)((a1 - (float)h1) * LO_SCALE);
  hidh[idx] = packh2(h0, h1);
  hidl[idx] = packh2(l0, l1);
}

// Pack W2 into MFMA A-fragment-linear fp16 hi / scaled-lo. (proven R8.
// R9 ERRATA: dropping the lo path -> absmax 2.0. NO precision cuts.)
__global__ void w2pack_kernel(const float* __restrict__ W2,
                              uint32_t* __restrict__ W2Fh, uint32_t* __restrict__ W2Fl) {
  int o = blockIdx.x * blockDim.x + threadIdx.x;   // 32768 threads
  int c = o >> 8, u = o & 255;
  int lane = u >> 2, pr = u & 3;
  int mtg = c >> 1, kh = c & 1;
  int row = mtg * 16 + (lane & 15);
  int k = kh * 32 + (lane >> 4) * 8 + pr * 2;
  float v0 = W2[(size_t)row * 64 + k];
  float v1 = W2[(size_t)row * 64 + k + 1];
  _Float16 h0 = (_Float16)v0, h1 = (_Float16)v1;
  _Float16 l0 = (_Float16)((v0 - (float)h0) * LO_SCALE);
  _Float16 l1 = (_Float16)((v1 - (float)h1) * LO_SCALE);
  W2Fh[o] = packh2(h0, h1);
  W2Fl[o] = packh2(l0, l1);
}

// ---------- CSR incidence build; hierarchical 3-phase scan (proven R6) ----
__global__ void zero_cur_kernel(int* __restrict__ cur) {
  int i = blockIdx.x * blockDim.x + threadIdx.x;
  if (i < N_NODES) cur[i] = 0;
}
__global__ void count_kernel(const int* __restrict__ edges, int* __restrict__ cur) {
  int e = blockIdx.x * blockDim.x + threadIdx.x;
  if (e < N_EDGES) {
    int s = edges[2 * e], d = edges[2 * e + 1];
    atomicAdd(&cur[s], 1);
    if (d != s) atomicAdd(&cur[d], 1);
  }
}
__global__ __launch_bounds__(256) void bsum_kernel(const int* __restrict__ cur,
                                                   int* __restrict__ bsum) {
  __shared__ int s[256];
  int b = blockIdx.x, t = threadIdx.x;
  int idx = b * 256 + t;
  s[t] = (idx < N_NODES) ? cur[idx] : 0;
  __syncthreads();
  for (int d = 128; d > 0; d >>= 1) {
    if (t < d) s[t] += s[t + d];
    __syncthreads();
  }
  if (t == 0) bsum[b] = s[0];
}
__global__ __launch_bounds__(256) void bscan_kernel(const int* __restrict__ bsum,
                                                    int* __restrict__ bbase,
                                                    int* __restrict__ off) {
  __shared__ int s[256];
  int t = threadIdx.x;
  int v = (t < SCAN_B) ? bsum[t] : 0;
  s[t] = v;
  __syncthreads();
  for (int d = 1; d < 256; d <<= 1) {
    int u = (t >= d) ? s[t - d] : 0;
    __syncthreads();
    s[t] += u;
    __syncthreads();
  }
  if (t < SCAN_B) bbase[t] = s[t] - v;        // exclusive block base
  if (t == SCAN_B - 1) off[N_NODES] = s[t];   // grand total
}
__global__ __launch_bounds__(256) void boff_kernel(const int* __restrict__ bbase,
                                                   int* __restrict__ cur,
                                                   int* __restrict__ off) {
  __shared__ int s[256];
  int b = blockIdx.x, t = threadIdx.x;
  int idx = b * 256 + t;
  int v = (idx < N_NODES) ? cur[idx] : 0;
  s[t] = v;
  __syncthreads();
  for (int d = 1; d < 256; d <<= 1) {
    int u = (t >= d) ? s[t - d] : 0;
    __syncthreads();
    s[t] += u;
    __syncthreads();
  }
  if (idx < N_NODES) {
    int ex = bbase[b] + s[t] - v;   // exclusive prefix
    off[idx] = ex;
    cur[idx] = ex;
  }
}
__global__ void scatter_kernel(const int* __restrict__ edges, int* __restrict__ cur,
                               int* __restrict__ inc) {
  int e = blockIdx.x * blockDim.x + threadIdx.x;
  if (e < N_EDGES) {
    int s = edges[2 * e], d = edges[2 * e + 1];
    int p = atomicAdd(&cur[s], 1);
    inc[p] = e;
    if (d != s) {
      p = atomicAdd(&cur[d], 1);
      inc[p] = e;
    }
  }
}

// ---------- async global->LDS helper (zero VGPR staging) ----------
typedef __attribute__((address_space(1))) const uint32_t gq_u32;
typedef __attribute__((address_space(3))) uint32_t lds_q_u32;
__device__ __forceinline__ void gload_lds16(const uint32_t* g, uint32_t* l) {
  // lds dst: wave-uniform base + lane*16B (hardware); global src per-lane.
  __builtin_amdgcn_global_load_lds((gq_u32*)g, (lds_q_u32*)l, 16, 0, 0);
}

// Stage one W2F SIXTEENTH (8KB hi + 8KB lo) into LDS buffers bh/bl.
// 4 waves x 2 calls x (64 lanes x 16B) = 8KB per array.
__device__ __forceinline__ void stage_16th(const uint32_t* __restrict__ W2Fh,
                                           const uint32_t* __restrict__ W2Fl,
                                           uint32_t* bh, uint32_t* bl,
                                           int s16, int wv, int lane) {
#pragma unroll
  for (int k = 0; k < 2; k++) {
    int ub = (wv * 2 + k) * 256;          // wave-uniform lds base (uint32 units)
    int u  = ub + lane * 4;               // per-lane global index (16B per lane)
    gload_lds16(W2Fh + s16 * 2048 + u, bh + ub);
    gload_lds16(W2Fl + s16 * 2048 + u, bl + ub);
  }
}

// R13: one single 16-stage sixteenth-granularity pass over NS edge-sets.
// R12 counters: msg Occupancy 17% (68KB LDS -> 2 blocks/CU), ~40% of time
// idle at per-stage barriers. Sixteenth staging: LDS 36KB -> 4 blocks/CU
// (16 waves), grid 1024 x ONE pass of 3-4 sets (3125/1024) -> no pass B,
// no cross-pass wraparound. ds_read/MFMA totals and W2F stream volume
// unchanged. Per-output-dim sums BIT-IDENTICAL to R8 (same tp-pairs per
// dim). Stores preserved at 16B/(q,h): half=0's two sacc values held in
// registers (+8 VGPR) and combined at half=1. NS<=4 (R7 spill lesson).
template <int NS>
__device__ __forceinline__ void do_pass(
    const uint32_t* __restrict__ W2Fh, const uint32_t* __restrict__ W2Fl,
    uint32_t (*w2h)[2048], uint32_t (*w2l)[2048], const float* b2s,
    const h8 (&bh0)[NS], const h8 (&bh1)[NS],
    const h8 (&bl0)[NS], const h8 (&bl1)[NS],
    const v4f (&xv0)[NS], const v4f (&xv1)[NS], const int (&ee)[NS],
    float* __restrict__ msg, int wv, int lane, int kg) {
  int cb = 0;
  float hold[NS][2];   // half=0 results, unroll-indexed only
  for (int s = 0; s < 16; ++s) {
    if (s < 15) {
      stage_16th(W2Fh, W2Fl, w2h[cb ^ 1], w2l[cb ^ 1], s + 1, wv, lane);
    }
    int q = s >> 2, h = (s >> 1) & 1, half = s & 1;
    const h8* sh = (const h8*)w2h[cb];
    const h8* sl = (const h8*)w2l[cb];

    float sacc[NS][2];   // [set][mp2']
#pragma unroll
    for (int mp2 = 0; mp2 < 2; mp2++) {
      float tacc[NS];
#pragma unroll
      for (int u = 0; u < NS; u++) tacc[u] = 0.f;
#pragma unroll
      for (int tp = 0; tp < 2; tp++) {
        int lml = 2 * mp2 + tp;            // sixteenth-local M-tile, 0..3
        h8 ah0 = sh[(size_t)(lml * 2 + 0) * 64 + lane];
        h8 ah1 = sh[(size_t)(lml * 2 + 1) * 64 + lane];
        h8 al0 = sl[(size_t)(lml * 2 + 0) * 64 + lane];
        h8 al1 = sl[(size_t)(lml * 2 + 1) * 64 + lane];
        int lm = half * 4 + lml;           // eighth-local tile, 0..7
        v4f bias = *(const v4f*)(b2s + q * 256 + h * 128 + lm * 16 + kg * 4);
#pragma unroll
        for (int u = 0; u < NS; u++) {
          v4f chi = bias;
          chi = __builtin_amdgcn_mfma_f32_16x16x32_f16(ah0, bh0[u], chi, 0, 0, 0);
          chi = __builtin_amdgcn_mfma_f32_16x16x32_f16(ah1, bh1[u], chi, 0, 0, 0);
          v4f clo = {0.f, 0.f, 0.f, 0.f};
          clo = __builtin_amdgcn_mfma_f32_16x16x32_f16(ah0, bl0[u], clo, 0, 0, 0);
          clo = __builtin_amdgcn_mfma_f32_16x16x32_f16(ah1, bl1[u], clo, 0, 0, 0);
          clo = __builtin_amdgcn_mfma_f32_16x16x32_f16(al0, bh0[u], clo, 0, 0, 0);
          clo = __builtin_amdgcn_mfma_f32_16x16x32_f16(al1, bh1[u], clo, 0, 0, 0);
          v4f xr = tp ? xv1[u] : xv0[u];
#pragma unroll
          for (int r = 0; r < 4; r++) {
            float av = fmaxf(fmaf(clo[r], LO_DESCALE, chi[r]), 0.f);
            tacc[u] = fmaf(av, xr[r], tacc[u]);
          }
        }
      }
#pragma unroll
      for (int u = 0; u < NS; u++) {
        float sv = tacc[u];
        sv += __shfl_xor(sv, 16, 64);
        sv += __shfl_xor(sv, 32, 64);
        sacc[u][mp2] = sv;   // msg value for (ee[u], i = q*8 + h*4 + half*2 + mp2)
      }
    }
    if (half == 0) {
#pragma unroll
      for (int u = 0; u < NS; u++) {
        hold[u][0] = sacc[u][0];
        hold[u][1] = sacc[u][1];
      }
    } else if (lane < 16) {
#pragma unroll
      for (int u = 0; u < NS; u++) {
        v4f sv4 = {hold[u][0], hold[u][1], sacc[u][0], sacc[u][1]};
        *(v4f*)(msg + (size_t)ee[u] * 32 + q * 8 + h * 4) = sv4;
      }
    }
    __syncthreads();   // drains global_load_lds (vmcnt) + LDS ops
    cb ^= 1;
  }
}

// Load the per-set edge inputs (hid fragments + x[src] rows) for NS groups
// starting at group gbase.
template <int NS>
__device__ __forceinline__ void load_sets(
    const uint32_t* __restrict__ hidh, const uint32_t* __restrict__ hidl,
    const float* __restrict__ x, const int* __restrict__ edges,
    int gbase, int wv, int el, int kg,
    h8 (&bh0)[NS], h8 (&bh1)[NS], h8 (&bl0)[NS], h8 (&bl1)[NS],
    v4f (&xv0)[NS], v4f (&xv1)[NS], int (&ee)[NS]) {
  const h8* hbh = (const h8*)hidh;
  const h8* hbl = (const h8*)hidl;
#pragma unroll
  for (int u = 0; u < NS; u++) {
    int e = (gbase + u) * 64 + wv * 16 + el;   // < 200000 (ranges partition NGROUPS)
    ee[u] = e;
    int src = edges[2 * e];
    bh0[u] = hbh[(size_t)e * 8 + kg];
    bh1[u] = hbh[(size_t)e * 8 + 4 + kg];
    bl0[u] = hbl[(size_t)e * 8 + kg];
    bl1[u] = hbl[(size_t)e * 8 + 4 + kg];
    xv0[u] = *(const v4f*)(x + (size_t)src * 32 + kg * 4);
    xv1[u] = *(const v4f*)(x + (size_t)src * 32 + 16 + kg * 4);
  }
}

// ---------- message build R13: grid 1024, 4 blocks/CU, single pass ----------
__global__ __launch_bounds__(256, 2) void msg_kernel(
    const uint32_t* __restrict__ W2Fh, const uint32_t* __restrict__ W2Fl,
    const uint32_t* __restrict__ hidh, const uint32_t* __restrict__ hidl,
    const float* __restrict__ b2, const float* __restrict__ x,
    const int* __restrict__ edges, float* __restrict__ msg) {
  __shared__ uint32_t w2h[2][2048];   // 2 x 8KB: sixteenth double-buffer, hi
  __shared__ uint32_t w2l[2][2048];   // 2 x 8KB: scaled lo
  __shared__ float b2s[1024];
  int t = threadIdx.x;
  int bid = blockIdx.x;
  // contiguous group range per block: grid 1024 -> 3 or 4 groups each
  int gs = (int)(((long)bid * NGROUPS) >> 10);
  int ge = (int)(((long)(bid + 1) * NGROUPS) >> 10);
  int n = ge - gs;                  // 3 or 4
  int wv = t >> 6, lane = t & 63;
  int el = lane & 15, kg = lane >> 4;

  for (int i = t; i < 1024; i += 256) b2s[i] = b2[i];
  // prologue: stage sixteenth 0 into buffer 0
  stage_16th(W2Fh, W2Fl, w2h[0], w2l[0], 0, wv, lane);

  if (n == 4) {
    h8 bh0[4], bh1[4], bl0[4], bl1[4];
    v4f xv0[4], xv1[4];
    int ee[4];
    load_sets<4>(hidh, hidl, x, edges, gs, wv, el, kg,
                 bh0, bh1, bl0, bl1, xv0, xv1, ee);
    __syncthreads();   // staging + b2s visible
    do_pass<4>(W2Fh, W2Fl, w2h, w2l, b2s, bh0, bh1, bl0, bl1, xv0, xv1, ee,
               msg, wv, lane, kg);
  } else {
    h8 bh0[3], bh1[3], bl0[3], bl1[3];
    v4f xv0[3], xv1[3];
    int ee[3];
    load_sets<3>(hidh, hidl, x, edges, gs, wv, el, kg,
                 bh0, bh1, bl0, bl1, xv0, xv1, ee);
    __syncthreads();
    do_pass<3>(W2Fh, W2Fl, w2h, w2l, b2s, bh0, bh1, bl0, bl1, xv0, xv1, ee,
               msg, wv, lane, kg);
  }
}

// ---------- per-iteration: CSR gather + GRU (proven R12: 8-way ILP gather) ----
__global__ __launch_bounds__(512) void node_kernel(
    float* __restrict__ x, const float* __restrict__ msg,
    const int* __restrict__ off, const int* __restrict__ inc,
    const float* __restrict__ W_ih, const float* __restrict__ W_hh,
    const float* __restrict__ b_ih, const float* __restrict__ b_hh) {
  __shared__ float wih[64 * 97];   // wih[k*97+q] = W_ih[q][k]
  __shared__ float whh[32 * 97];
  __shared__ float xs[16][32], ms[16][32];
  int t = threadIdx.x;
  for (int p = t; p < 6144; p += 512) {
    int q = p >> 6, k = p & 63;
    wih[k * 97 + q] = W_ih[p];
  }
  for (int p = t; p < 3072; p += 512) {
    int q = p >> 5, k = p & 31;
    whh[k * 97 + q] = W_hh[p];
  }
  int slot = t >> 5, i = t & 31;
  int n = blockIdx.x * 16 + slot;   // 3125*16 = 50000 exact
  float xv = x[(size_t)n * 32 + i];
  xs[slot][i] = xv;
  const float* msgq = msg + i;      // edge-major: msg[e*32 + i]
  int s0 = off[n], s1 = off[n + 1];
  float a0 = 0.f, a1 = 0.f, a2 = 0.f, a3 = 0.f;
  float a4 = 0.f, a5 = 0.f, a6 = 0.f, a7 = 0.f;
  int k = s0;
  for (; k + 8 <= s1; k += 8) {     // 8 independent lines in flight
    int e0 = inc[k],     e1 = inc[k + 1], e2 = inc[k + 2], e3 = inc[k + 3];
    int e4 = inc[k + 4], e5 = inc[k + 5], e6 = inc[k + 6], e7 = inc[k + 7];
    a0 += msgq[(size_t)e0 * 32];
    a1 += msgq[(size_t)e1 * 32];
    a2 += msgq[(size_t)e2 * 32];
    a3 += msgq[(size_t)e3 * 32];
    a4 += msgq[(size_t)e4 * 32];
    a5 += msgq[(size_t)e5 * 32];
    a6 += msgq[(size_t)e6 * 32];
    a7 += msgq[(size_t)e7 * 32];
  }
  if (k + 4 <= s1) {                // 4-wide step
    int e0 = inc[k], e1 = inc[k + 1], e2 = inc[k + 2], e3 = inc[k + 3];
    a0 += msgq[(size_t)e0 * 32];
    a1 += msgq[(size_t)e1 * 32];
    a2 += msgq[(size_t)e2 * 32];
    a3 += msgq[(size_t)e3 * 32];
    k += 4;
  }
  for (; k < s1; k++) a0 += msgq[(size_t)inc[k] * 32];
  ms[slot][i] = ((a0 + a1) + (a2 + a3)) + ((a4 + a5) + (a6 + a7));
  __syncthreads();

  float gir = b_ih[i], giz = b_ih[32 + i], gin = b_ih[64 + i];
  float ghr = b_hh[i], ghz = b_hh[32 + i], ghn = b_hh[64 + i];
#pragma unroll 4
  for (int kk = 0; kk < 32; kk++) {
    float xk = xs[slot][kk];
    float mk = ms[slot][kk];
    const float* wa = &wih[kk * 97];          // W_ih[.][k]     (x part)
    const float* wb = &wih[(32 + kk) * 97];   // W_ih[.][32+k]  (m part)
    gir += xk * wa[i] + mk * wb[i];
    giz += xk * wa[32 + i] + mk * wb[32 + i];
    gin += xk * wa[64 + i] + mk * wb[64 + i];
    const float* hc = &whh[kk * 97];
    ghr += xk * hc[i];
    ghz += xk * hc[32 + i];
    ghn += xk * hc[64 + i];
  }
  float r = 1.f / (1.f + __expf(-(gir + ghr)));
  float z = 1.f / (1.f + __expf(-(giz + ghz)));
  float nn = tanhf(gin + r * ghn);
  x[(size_t)n * 32 + i] = (1.f - z) * nn + z * xv;
}

__global__ void copy4_kernel(float4* __restrict__ dst, const float4* __restrict__ src, int n4) {
  int i = blockIdx.x * blockDim.x + threadIdx.x;
  if (i < n4) dst[i] = src[i];
}

extern "C" void kernel_launch(void* const* d_in, const int* in_sizes, int n_in,
                              void* d_out, int out_size, void* d_ws, size_t ws_size,
                              hipStream_t stream) {
  const float* x_in      = (const float*)d_in[0];
  const float* edge_data = (const float*)d_in[1];
  const int*   edges     = (const int*)d_in[2];
  // d_in[3] = T (always 8; hard-coded)
  const float* W1   = (const float*)d_in[4];
  const float* b1   = (const float*)d_in[5];
  const float* W2   = (const float*)d_in[6];
  const float* b2   = (const float*)d_in[7];
  const float* W_ih = (const float*)d_in[8];
  const float* W_hh = (const float*)d_in[9];
  const float* b_ih = (const float*)d_in[10];
  const float* b_hh = (const float*)d_in[11];

  // Workspace ~79.08 MB (< 83.59 MB proven bound):
  // hidh 25.6M | hidl 25.6M | W2F 256K | W1P 4K | inc 1.6M | off | cur | bsum/bbase | msg 25.6M
  char* ws = (char*)d_ws;
  size_t o = 0;
  uint32_t* hidh = (uint32_t*)(ws + o); o += (size_t)N_EDGES * 64 * 2;
  uint32_t* hidl = (uint32_t*)(ws + o); o += (size_t)N_EDGES * 64 * 2;
  uint32_t* W2Fh = (uint32_t*)(ws + o); o += 32768u * 4;
  uint32_t* W2Fl = (uint32_t*)(ws + o); o += 32768u * 4;
  float*    W1P  = (float*)(ws + o);    o += 1024u * 4;
  int*      inc  = (int*)(ws + o);      o += (size_t)2 * N_EDGES * 4;
  int*      off  = (int*)(ws + o);      o += (size_t)(N_NODES + 4) * 4;
  int*      cur  = (int*)(ws + o);      o += (size_t)N_NODES * 4;
  int*      bsum = (int*)(ws + o);      o += (size_t)256 * 4;
  int*      bbase= (int*)(ws + o);      o += (size_t)256 * 4;
  float*    msg  = (float*)(ws + o);    o += (size_t)N_EDGES * 32 * 4;
  float*    x    = (float*)d_out;   // iterate x in-place in d_out

  const int n4x = N_NODES * H / 4;  // 400000
  copy4_kernel<<<(n4x + 255) / 256, 256, 0, stream>>>((float4*)x, (const float4*)x_in, n4x);
  w1pack_kernel<<<4, 256, 0, stream>>>(W1, W1P);
  hidb_kernel<<<N_EDGES * 32 / 256, 256, 0, stream>>>(edge_data, W1P, b1, hidh, hidl);
  w2pack_kernel<<<32768 / 256, 256, 0, stream>>>(W2, W2Fh, W2Fl);

  zero_cur_kernel<<<(N_NODES + 255) / 256, 256, 0, stream>>>(cur);
  count_kernel<<<(N_EDGES + 255) / 256, 256, 0, stream>>>(edges, cur);
  bsum_kernel<<<SCAN_B, 256, 0, stream>>>(cur, bsum);
  bscan_kernel<<<1, 256, 0, stream>>>(bsum, bbase, off);
  boff_kernel<<<SCAN_B, 256, 0, stream>>>(bbase, cur, off);
  scatter_kernel<<<(N_EDGES + 255) / 256, 256, 0, stream>>>(edges, cur, inc);

  for (int it = 0; it < T_STEPS; it++) {
    msg_kernel<<<MSG_GRID, 256, 0, stream>>>(W2Fh, W2Fl, hidh, hidl, b2, x, edges, msg);
    node_kernel<<<N_NODES / 16, 512, 0, stream>>>(x, msg, off, inc,
                                                  W_ih, W_hh, b_ih, b_hh);
  }
}

// Round 14
// 1335.147 us; speedup vs baseline: 1.0646x; 1.0646x over previous
//
#include <hip/hip_runtime.h>
#include <stdint.h>

#define N_NODES 50000
#define N_EDGES 200000
#define H 32
#define T_STEPS 8
#define NGROUPS (N_EDGES / 64)   // 3125
#define SCAN_B 196               // 196*256 = 50176 >= N_NODES

typedef __attribute__((ext_vector_type(4))) float v4f;
typedef __attribute__((ext_vector_type(8))) _Float16 h8;

#define LO_SCALE 4096.0f
#define LO_DESCALE 2.44140625e-4f  // 1/4096

__device__ __forceinline__ uint32_t packh2(_Float16 a, _Float16 b) {
  return (uint32_t)__builtin_bit_cast(unsigned short, a) |
         ((uint32_t)__builtin_bit_cast(unsigned short, b) << 16);
}

// Transpose W1 (64x16 -> 16x64) so hidb's per-lane reads are coalesced. (R12 win)
__global__ void w1pack_kernel(const float* __restrict__ W1, float* __restrict__ W1P) {
  int o = threadIdx.x + blockIdx.x * blockDim.x;   // 1024 threads
  int d = o >> 4, k = o & 15;
  W1P[k * 64 + d] = W1[o];
}

// hid[e][d] = relu(edge_data[e].W1[d] + b1[d]), fp16 hi + scaled-lo. (R12: 108->~25us)
__global__ void hidb_kernel(const float* __restrict__ ed, const float* __restrict__ W1P,
                            const float* __restrict__ b1,
                            uint32_t* __restrict__ hidh, uint32_t* __restrict__ hidl) {
  int idx = blockIdx.x * blockDim.x + threadIdx.x;   // E*32 threads
  int e = idx >> 5, d2 = idx & 31;
  int d0 = d2 * 2;
  const float4* er = (const float4*)(ed + (size_t)e * 16);
  float2 bb = *(const float2*)(b1 + d0);
  float a0 = bb.x, a1 = bb.y;
#pragma unroll
  for (int k = 0; k < 4; k++) {
    float4 h = er[k];
    float2 w0 = *(const float2*)(W1P + (4 * k + 0) * 64 + d0);
    float2 w1 = *(const float2*)(W1P + (4 * k + 1) * 64 + d0);
    float2 w2 = *(const float2*)(W1P + (4 * k + 2) * 64 + d0);
    float2 w3 = *(const float2*)(W1P + (4 * k + 3) * 64 + d0);
    a0 += h.x * w0.x + h.y * w1.x + h.z * w2.x + h.w * w3.x;
    a1 += h.x * w0.y + h.y * w1.y + h.z * w2.y + h.w * w3.y;
  }
  a0 = fmaxf(a0, 0.f);
  a1 = fmaxf(a1, 0.f);
  _Float16 h0 = (_Float16)a0, h1 = (_Float16)a1;
  _Float16 l0 = (_Float16)((a0 - (float)h0) * LO_SCALE);
  _Float16 l1 = (_Float16)((a1 - (float)h1) * LO_SCALE);
  hidh[idx] = packh2(h0, h1);
  hidl[idx] = packh2(l0, l1);
}

// Pack W2 into MFMA A-fragment-linear fp16 hi / scaled-lo. (proven R8.
// R9 ERRATA: dropping the lo path -> absmax 2.0. NO precision cuts.)
__global__ void w2pack_kernel(const float* __restrict__ W2,
                              uint32_t* __restrict__ W2Fh, uint32_t* __restrict__ W2Fl) {
  int o = blockIdx.x * blockDim.x + threadIdx.x;   // 32768 threads
  int c = o >> 8, u = o & 255;
  int lane = u >> 2, pr = u & 3;
  int mtg = c >> 1, kh = c & 1;
  int row = mtg * 16 + (lane & 15);
  int k = kh * 32 + (lane >> 4) * 8 + pr * 2;
  float v0 = W2[(size_t)row * 64 + k];
  float v1 = W2[(size_t)row * 64 + k + 1];
  _Float16 h0 = (_Float16)v0, h1 = (_Float16)v1;
  _Float16 l0 = (_Float16)((v0 - (float)h0) * LO_SCALE);
  _Float16 l1 = (_Float16)((v1 - (float)h1) * LO_SCALE);
  W2Fh[o] = packh2(h0, h1);
  W2Fl[o] = packh2(l0, l1);
}

// ---------- CSR incidence build; hierarchical 3-phase scan (proven R6) ----
__global__ void zero_cur_kernel(int* __restrict__ cur) {
  int i = blockIdx.x * blockDim.x + threadIdx.x;
  if (i < N_NODES) cur[i] = 0;
}
__global__ void count_kernel(const int* __restrict__ edges, int* __restrict__ cur) {
  int e = blockIdx.x * blockDim.x + threadIdx.x;
  if (e < N_EDGES) {
    int s = edges[2 * e], d = edges[2 * e + 1];
    atomicAdd(&cur[s], 1);
    if (d != s) atomicAdd(&cur[d], 1);
  }
}
__global__ __launch_bounds__(256) void bsum_kernel(const int* __restrict__ cur,
                                                   int* __restrict__ bsum) {
  __shared__ int s[256];
  int b = blockIdx.x, t = threadIdx.x;
  int idx = b * 256 + t;
  s[t] = (idx < N_NODES) ? cur[idx] : 0;
  __syncthreads();
  for (int d = 128; d > 0; d >>= 1) {
    if (t < d) s[t] += s[t + d];
    __syncthreads();
  }
  if (t == 0) bsum[b] = s[0];
}
__global__ __launch_bounds__(256) void bscan_kernel(const int* __restrict__ bsum,
                                                    int* __restrict__ bbase,
                                                    int* __restrict__ off) {
  __shared__ int s[256];
  int t = threadIdx.x;
  int v = (t < SCAN_B) ? bsum[t] : 0;
  s[t] = v;
  __syncthreads();
  for (int d = 1; d < 256; d <<= 1) {
    int u = (t >= d) ? s[t - d] : 0;
    __syncthreads();
    s[t] += u;
    __syncthreads();
  }
  if (t < SCAN_B) bbase[t] = s[t] - v;        // exclusive block base
  if (t == SCAN_B - 1) off[N_NODES] = s[t];   // grand total
}
__global__ __launch_bounds__(256) void boff_kernel(const int* __restrict__ bbase,
                                                   int* __restrict__ cur,
                                                   int* __restrict__ off) {
  __shared__ int s[256];
  int b = blockIdx.x, t = threadIdx.x;
  int idx = b * 256 + t;
  int v = (idx < N_NODES) ? cur[idx] : 0;
  s[t] = v;
  __syncthreads();
  for (int d = 1; d < 256; d <<= 1) {
    int u = (t >= d) ? s[t - d] : 0;
    __syncthreads();
    s[t] += u;
    __syncthreads();
  }
  if (idx < N_NODES) {
    int ex = bbase[b] + s[t] - v;   // exclusive prefix
    off[idx] = ex;
    cur[idx] = ex;
  }
}
__global__ void scatter_kernel(const int* __restrict__ edges, int* __restrict__ cur,
                               int* __restrict__ inc) {
  int e = blockIdx.x * blockDim.x + threadIdx.x;
  if (e < N_EDGES) {
    int s = edges[2 * e], d = edges[2 * e + 1];
    int p = atomicAdd(&cur[s], 1);
    inc[p] = e;
    if (d != s) {
      p = atomicAdd(&cur[d], 1);
      inc[p] = e;
    }
  }
}

// ---------- async global->LDS helper (zero VGPR staging) ----------
typedef __attribute__((address_space(1))) const uint32_t gq_u32;
typedef __attribute__((address_space(3))) uint32_t lds_q_u32;
__device__ __forceinline__ void gload_lds16(const uint32_t* g, uint32_t* l) {
  // lds dst: wave-uniform base + lane*16B (hardware); global src per-lane.
  __builtin_amdgcn_global_load_lds((gq_u32*)g, (lds_q_u32*)l, 16, 0, 0);
}

// Stage one W2F eighth (16KB hi + 16KB lo) into LDS buffers bh/bl.
// 4 waves x 4 calls x (64 lanes x 16B) = 16KB per array.
__device__ __forceinline__ void stage_eighth(const uint32_t* __restrict__ W2Fh,
                                             const uint32_t* __restrict__ W2Fl,
                                             uint32_t* bh, uint32_t* bl,
                                             int eighth, int wv, int lane) {
#pragma unroll
  for (int k = 0; k < 4; k++) {
    int ub = (wv * 4 + k) * 256;          // wave-uniform lds base (uint32 units)
    int u  = ub + lane * 4;               // per-lane global index (16B per lane)
    gload_lds16(W2Fh + eighth * 4096 + u, bh + ub);
    gload_lds16(W2Fl + eighth * 4096 + u, bl + ub);
  }
}

// One full 8-stage W2 stream pass over NS edge-sets. Fully unrolled over NS
// (compile-time) so all set arrays stay register-resident (R7 lesson: the
// VGPR ceiling here is 128; 5 sets spilled hot state to scratch -> +150MB
// HBM, 2x regression. NS<=4 only).
// R13 lesson: sixteenth-granularity staging (more stages, less work each)
// regresses — msg idle is per-stage fixed overhead x stage count, NOT
// LDS-capacity-capped occupancy (occupancy stayed 16% despite 36KB LDS).
template <int NS>
__device__ __forceinline__ void do_pass(
    const uint32_t* __restrict__ W2Fh, const uint32_t* __restrict__ W2Fl,
    uint32_t (*w2h)[4096], uint32_t (*w2l)[4096], const float* b2s,
    const h8 (&bh0)[NS], const h8 (&bh1)[NS],
    const h8 (&bl0)[NS], const h8 (&bl1)[NS],
    const v4f (&xv0)[NS], const v4f (&xv1)[NS], const int (&ee)[NS],
    float* __restrict__ msg, int wv, int lane, int kg, bool last) {
  int cb = 0;
  for (int s = 0; s < 8; ++s) {
    if (!(last && s == 7)) {
      stage_eighth(W2Fh, W2Fl, w2h[cb ^ 1], w2l[cb ^ 1], (s + 1) & 7, wv, lane);
    }
    int q = s >> 1, h = s & 1;
    const h8* sh = (const h8*)w2h[cb];
    const h8* sl = (const h8*)w2l[cb];
    const float* b2p = b2s + q * 256 + h * 128 + kg * 4;

    float sacc[NS][4];   // [set][mp2]
#pragma unroll
    for (int mp2 = 0; mp2 < 4; mp2++) {
      float tacc[NS];
#pragma unroll
      for (int u = 0; u < NS; u++) tacc[u] = 0.f;
#pragma unroll
      for (int tp = 0; tp < 2; tp++) {
        int lm = 2 * mp2 + tp;   // within-eighth M-tile, 0..7
        h8 ah0 = sh[(size_t)(lm * 2 + 0) * 64 + lane];
        h8 ah1 = sh[(size_t)(lm * 2 + 1) * 64 + lane];
        h8 al0 = sl[(size_t)(lm * 2 + 0) * 64 + lane];
        h8 al1 = sl[(size_t)(lm * 2 + 1) * 64 + lane];
        v4f bias = *(const v4f*)(b2p + lm * 16);
#pragma unroll
        for (int u = 0; u < NS; u++) {
          v4f chi = bias;
          chi = __builtin_amdgcn_mfma_f32_16x16x32_f16(ah0, bh0[u], chi, 0, 0, 0);
          chi = __builtin_amdgcn_mfma_f32_16x16x32_f16(ah1, bh1[u], chi, 0, 0, 0);
          v4f clo = {0.f, 0.f, 0.f, 0.f};
          clo = __builtin_amdgcn_mfma_f32_16x16x32_f16(ah0, bl0[u], clo, 0, 0, 0);
          clo = __builtin_amdgcn_mfma_f32_16x16x32_f16(ah1, bl1[u], clo, 0, 0, 0);
          clo = __builtin_amdgcn_mfma_f32_16x16x32_f16(al0, bh0[u], clo, 0, 0, 0);
          clo = __builtin_amdgcn_mfma_f32_16x16x32_f16(al1, bh1[u], clo, 0, 0, 0);
          v4f xr = tp ? xv1[u] : xv0[u];
#pragma unroll
          for (int r = 0; r < 4; r++) {
            float av = fmaxf(fmaf(clo[r], LO_DESCALE, chi[r]), 0.f);
            tacc[u] = fmaf(av, xr[r], tacc[u]);
          }
        }
      }
#pragma unroll
      for (int u = 0; u < NS; u++) {
        float sv = tacc[u];
        sv += __shfl_xor(sv, 16, 64);
        sv += __shfl_xor(sv, 32, 64);
        sacc[u][mp2] = sv;   // msg value for (ee[u], i = q*8 + h*4 + mp2)
      }
    }
    if (lane < 16) {
#pragma unroll
      for (int u = 0; u < NS; u++) {
        v4f sv4 = {sacc[u][0], sacc[u][1], sacc[u][2], sacc[u][3]};
        *(v4f*)(msg + (size_t)ee[u] * 32 + q * 8 + h * 4) = sv4;
      }
    }
    __syncthreads();   // drains global_load_lds (vmcnt) + LDS ops
    cb ^= 1;
  }
}

// Load the per-set edge inputs (hid fragments + x[src] rows) for NS groups
// starting at group gbase.
template <int NS>
__device__ __forceinline__ void load_sets(
    const uint32_t* __restrict__ hidh, const uint32_t* __restrict__ hidl,
    const float* __restrict__ x, const int* __restrict__ edges,
    int gbase, int wv, int el, int kg,
    h8 (&bh0)[NS], h8 (&bh1)[NS], h8 (&bl0)[NS], h8 (&bl1)[NS],
    v4f (&xv0)[NS], v4f (&xv1)[NS], int (&ee)[NS]) {
  const h8* hbh = (const h8*)hidh;
  const h8* hbl = (const h8*)hidl;
#pragma unroll
  for (int u = 0; u < NS; u++) {
    int e = (gbase + u) * 64 + wv * 16 + el;   // < 200000 (ranges partition NGROUPS)
    ee[u] = e;
    int src = edges[2 * e];
    bh0[u] = hbh[(size_t)e * 8 + kg];
    bh1[u] = hbh[(size_t)e * 8 + 4 + kg];
    bl0[u] = hbl[(size_t)e * 8 + kg];
    bl1[u] = hbl[(size_t)e * 8 + 4 + kg];
    xv0[u] = *(const v4f*)(x + (size_t)src * 32 + kg * 4);
    xv1[u] = *(const v4f*)(x + (size_t)src * 32 + 16 + kg * 4);
  }
}

// ---------- message build (proven R12: grid 512, 4-set pass A + exact
// 2/3-set pass B, full hi/lo compensation, eighth-granularity staging) ----
__global__ __launch_bounds__(256, 2) void msg_kernel(
    const uint32_t* __restrict__ W2Fh, const uint32_t* __restrict__ W2Fl,
    const uint32_t* __restrict__ hidh, const uint32_t* __restrict__ hidl,
    const float* __restrict__ b2, const float* __restrict__ x,
    const int* __restrict__ edges, float* __restrict__ msg) {
  __shared__ uint32_t w2h[2][4096];   // 2 x 16KB: eighth double-buffer, hi
  __shared__ uint32_t w2l[2][4096];   // 2 x 16KB: scaled lo
  __shared__ float b2s[1024];
  int t = threadIdx.x;
  int bid = blockIdx.x;
  // contiguous group range per block: grid 512 -> 6 or 7 groups each
  int gs = (int)(((long)bid * NGROUPS) >> 9);
  int ge = (int)(((long)(bid + 1) * NGROUPS) >> 9);
  int n = ge - gs;                  // 6 or 7
  int wv = t >> 6, lane = t & 63;
  int el = lane & 15, kg = lane >> 4;

  for (int i = t; i < 1024; i += 256) b2s[i] = b2[i];
  // prologue: stage eighth 0 into buffer 0
  stage_eighth(W2Fh, W2Fl, w2h[0], w2l[0], 0, wv, lane);

  // pass A set data (loads overlap the staging latency; barrier below)
  h8 bh0[4], bh1[4], bl0[4], bl1[4];
  v4f xv0[4], xv1[4];
  int ee[4];
  load_sets<4>(hidh, hidl, x, edges, gs, wv, el, kg,
               bh0, bh1, bl0, bl1, xv0, xv1, ee);
  __syncthreads();

  // ---- pass A: 4 sets, stages all 8 eighths, re-stages eighth 0 at s=7 ----
  do_pass<4>(W2Fh, W2Fl, w2h, w2l, b2s, bh0, bh1, bl0, bl1, xv0, xv1, ee,
             msg, wv, lane, kg, /*last=*/false);

  __builtin_amdgcn_sched_barrier(0);   // keep pass B loads from hoisting into A

  // ---- pass B: exactly n-4 sets (2 or 3), last pass ----
  if (n == 6) {
    h8 cbh0[2], cbh1[2], cbl0[2], cbl1[2];
    v4f cxv0[2], cxv1[2];
    int cee[2];
    load_sets<2>(hidh, hidl, x, edges, gs + 4, wv, el, kg,
                 cbh0, cbh1, cbl0, cbl1, cxv0, cxv1, cee);
    do_pass<2>(W2Fh, W2Fl, w2h, w2l, b2s, cbh0, cbh1, cbl0, cbl1,
               cxv0, cxv1, cee, msg, wv, lane, kg, /*last=*/true);
  } else {
    h8 cbh0[3], cbh1[3], cbl0[3], cbl1[3];
    v4f cxv0[3], cxv1[3];
    int cee[3];
    load_sets<3>(hidh, hidl, x, edges, gs + 4, wv, el, kg,
                 cbh0, cbh1, cbl0, cbl1, cxv0, cxv1, cee);
    do_pass<3>(W2Fh, W2Fl, w2h, w2l, b2s, cbh0, cbh1, cbl0, cbl1,
               cxv0, cxv1, cee, msg, wv, lane, kg, /*last=*/true);
  }
}

// ---------- per-iteration: CSR gather + GRU (proven R12: 8-way ILP gather).
// R14: split read/write pointers so iteration 0 reads x_in directly and
// copy4 is eliminated (xr==xw for it>=1; x_in never written -> re-entrant).
__global__ __launch_bounds__(512) void node_kernel(
    const float* __restrict__ xr, float* __restrict__ xw,
    const float* __restrict__ msg,
    const int* __restrict__ off, const int* __restrict__ inc,
    const float* __restrict__ W_ih, const float* __restrict__ W_hh,
    const float* __restrict__ b_ih, const float* __restrict__ b_hh) {
  __shared__ float wih[64 * 97];   // wih[k*97+q] = W_ih[q][k]
  __shared__ float whh[32 * 97];
  __shared__ float xs[16][32], ms[16][32];
  int t = threadIdx.x;
  for (int p = t; p < 6144; p += 512) {
    int q = p >> 6, k = p & 63;
    wih[k * 97 + q] = W_ih[p];
  }
  for (int p = t; p < 3072; p += 512) {
    int q = p >> 5, k = p & 31;
    whh[k * 97 + q] = W_hh[p];
  }
  int slot = t >> 5, i = t & 31;
  int n = blockIdx.x * 16 + slot;   // 3125*16 = 50000 exact
  float xv = xr[(size_t)n * 32 + i];
  xs[slot][i] = xv;
  const float* msgq = msg + i;      // edge-major: msg[e*32 + i]
  int s0 = off[n], s1 = off[n + 1];
  float a0 = 0.f, a1 = 0.f, a2 = 0.f, a3 = 0.f;
  float a4 = 0.f, a5 = 0.f, a6 = 0.f, a7 = 0.f;
  int k = s0;
  for (; k + 8 <= s1; k += 8) {     // 8 independent lines in flight
    int e0 = inc[k],     e1 = inc[k + 1], e2 = inc[k + 2], e3 = inc[k + 3];
    int e4 = inc[k + 4], e5 = inc[k + 5], e6 = inc[k + 6], e7 = inc[k + 7];
    a0 += msgq[(size_t)e0 * 32];
    a1 += msgq[(size_t)e1 * 32];
    a2 += msgq[(size_t)e2 * 32];
    a3 += msgq[(size_t)e3 * 32];
    a4 += msgq[(size_t)e4 * 32];
    a5 += msgq[(size_t)e5 * 32];
    a6 += msgq[(size_t)e6 * 32];
    a7 += msgq[(size_t)e7 * 32];
  }
  if (k + 4 <= s1) {                // 4-wide step
    int e0 = inc[k], e1 = inc[k + 1], e2 = inc[k + 2], e3 = inc[k + 3];
    a0 += msgq[(size_t)e0 * 32];
    a1 += msgq[(size_t)e1 * 32];
    a2 += msgq[(size_t)e2 * 32];
    a3 += msgq[(size_t)e3 * 32];
    k += 4;
  }
  for (; k < s1; k++) a0 += msgq[(size_t)inc[k] * 32];
  ms[slot][i] = ((a0 + a1) + (a2 + a3)) + ((a4 + a5) + (a6 + a7));
  __syncthreads();

  float gir = b_ih[i], giz = b_ih[32 + i], gin = b_ih[64 + i];
  float ghr = b_hh[i], ghz = b_hh[32 + i], ghn = b_hh[64 + i];
#pragma unroll 4
  for (int kk = 0; kk < 32; kk++) {
    float xk = xs[slot][kk];
    float mk = ms[slot][kk];
    const float* wa = &wih[kk * 97];          // W_ih[.][k]     (x part)
    const float* wb = &wih[(32 + kk) * 97];   // W_ih[.][32+k]  (m part)
    gir += xk * wa[i] + mk * wb[i];
    giz += xk * wa[32 + i] + mk * wb[32 + i];
    gin += xk * wa[64 + i] + mk * wb[64 + i];
    const float* hc = &whh[kk * 97];
    ghr += xk * hc[i];
    ghz += xk * hc[32 + i];
    ghn += xk * hc[64 + i];
  }
  float r = 1.f / (1.f + __expf(-(gir + ghr)));
  float z = 1.f / (1.f + __expf(-(giz + ghz)));
  float nn = tanhf(gin + r * ghn);
  xw[(size_t)n * 32 + i] = (1.f - z) * nn + z * xv;
}

extern "C" void kernel_launch(void* const* d_in, const int* in_sizes, int n_in,
                              void* d_out, int out_size, void* d_ws, size_t ws_size,
                              hipStream_t stream) {
  const float* x_in      = (const float*)d_in[0];
  const float* edge_data = (const float*)d_in[1];
  const int*   edges     = (const int*)d_in[2];
  // d_in[3] = T (always 8; hard-coded)
  const float* W1   = (const float*)d_in[4];
  const float* b1   = (const float*)d_in[5];
  const float* W2   = (const float*)d_in[6];
  const float* b2   = (const float*)d_in[7];
  const float* W_ih = (const float*)d_in[8];
  const float* W_hh = (const float*)d_in[9];
  const float* b_ih = (const float*)d_in[10];
  const float* b_hh = (const float*)d_in[11];

  // Workspace ~79.08 MB (< 83.59 MB proven bound):
  // hidh 25.6M | hidl 25.6M | W2F 256K | W1P 4K | inc 1.6M | off | cur | bsum/bbase | msg 25.6M
  char* ws = (char*)d_ws;
  size_t o = 0;
  uint32_t* hidh = (uint32_t*)(ws + o); o += (size_t)N_EDGES * 64 * 2;
  uint32_t* hidl = (uint32_t*)(ws + o); o += (size_t)N_EDGES * 64 * 2;
  uint32_t* W2Fh = (uint32_t*)(ws + o); o += 32768u * 4;
  uint32_t* W2Fl = (uint32_t*)(ws + o); o += 32768u * 4;
  float*    W1P  = (float*)(ws + o);    o += 1024u * 4;
  int*      inc  = (int*)(ws + o);      o += (size_t)2 * N_EDGES * 4;
  int*      off  = (int*)(ws + o);      o += (size_t)(N_NODES + 4) * 4;
  int*      cur  = (int*)(ws + o);      o += (size_t)N_NODES * 4;
  int*      bsum = (int*)(ws + o);      o += (size_t)256 * 4;
  int*      bbase= (int*)(ws + o);      o += (size_t)256 * 4;
  float*    msg  = (float*)(ws + o);    o += (size_t)N_EDGES * 32 * 4;
  float*    x    = (float*)d_out;   // iterate x in-place in d_out (it0 reads x_in)

  w1pack_kernel<<<4, 256, 0, stream>>>(W1, W1P);
  hidb_kernel<<<N_EDGES * 32 / 256, 256, 0, stream>>>(edge_data, W1P, b1, hidh, hidl);
  w2pack_kernel<<<32768 / 256, 256, 0, stream>>>(W2, W2Fh, W2Fl);

  zero_cur_kernel<<<(N_NODES + 255) / 256, 256, 0, stream>>>(cur);
  count_kernel<<<(N_EDGES + 255) / 256, 256, 0, stream>>>(edges, cur);
  bsum_kernel<<<SCAN_B, 256, 0, stream>>>(cur, bsum);
  bscan_kernel<<<1, 256, 0, stream>>>(bsum, bbase, off);
  boff_kernel<<<SCAN_B, 256, 0, stream>>>(bbase, cur, off);
  scatter_kernel<<<(N_EDGES + 255) / 256, 256, 0, stream>>>(edges, cur, inc);

  for (int it = 0; it < T_STEPS; it++) {
    const float* xcur = (it == 0) ? x_in : x;   // it0 reads inputs directly
    msg_kernel<<<512, 256, 0, stream>>>(W2Fh, W2Fl, hidh, hidl, b2, xcur, edges, msg);
    node_kernel<<<N_NODES / 16, 512, 0, stream>>>(xcur, x, msg, off, inc,
                                                  W_ih, W_hh, b_ih, b_hh);
  }
}